// Round 6
// baseline (594.005 us; speedup 1.0000x reference)
//
#include <hip/hip_runtime.h>

#define NN 32      // nodes
#define FF 64      // GAT out features
#define HH 128     // LSTM hidden
#define G4 512     // 4*H
#define BB 32      // batch
#define TT 512     // time steps
#define ET 128     // 96 edges + 32 self loops
#define NPOS (BB*TT)

__device__ __forceinline__ float frcp(float x) { return __builtin_amdgcn_rcpf(x); }

// ---------------- prep: fold GAT linear into LSTM input weights + Wt transpose ----------------
// R13/R18 weight layout: Wt[tid*128 + g*32 + kk] = W_hh[(kq*32+kk)][g*128 + r], tid=r*4+kq
__global__ __launch_bounds__(512) void prep_kernel(const float* __restrict__ w_gat,
                                                   const float* __restrict__ b_gat,
                                                   const float* __restrict__ W_ih,
                                                   const float* __restrict__ W_hh,
                                                   float* __restrict__ W_eff,
                                                   float* __restrict__ biasp,
                                                   float* __restrict__ Wt) {
  int j = threadIdx.x;
  int n = blockIdx.x;
  float accw = 0.f, accb = 0.f;
#pragma unroll 8
  for (int f = 0; f < FF; ++f) {
    float wv = W_ih[(n * FF + f) * G4 + j];
    accw = fmaf(w_gat[f], wv, accw);
    accb = fmaf(b_gat[f], wv, accb);
  }
  W_eff[n * G4 + j] = accw;
  biasp[n * G4 + j] = accb;
  int g0 = (n * G4 + j) * 4;
#pragma unroll
  for (int q = 0; q < 4; ++q) {
    int e = g0 + q;
    int tl = e >> 7, idx = e & 127;
    int r = tl >> 2, kq = tl & 3;
    int g = idx >> 5, kk = idx & 31;
    Wt[e] = W_hh[(kq * 32 + kk) * G4 + g * 128 + r];
  }
}

// ---------------- fused GAT + xw (+ block-local bias/sort/scal) ----------------
__global__ __launch_bounds__(256) void gatxw_kernel(const float* __restrict__ x_seq,
                                                    const int* __restrict__ ei,
                                                    const float* __restrict__ w_gat,
                                                    const float* __restrict__ att_src,
                                                    const float* __restrict__ att_dst,
                                                    const float* __restrict__ b_ih,
                                                    const float* __restrict__ b_hh,
                                                    const float* __restrict__ W_eff,
                                                    const float* __restrict__ biasp,
                                                    float* __restrict__ xw) {
  __shared__ int srt[ET];
  __shared__ int offs[NN + 1];
  __shared__ int cnt[NN];
  __shared__ float xs[256];
  __shared__ float sl[256];
  __shared__ float scal_sh[2];
  int tid = threadIdx.x;
  int posbase = blockIdx.x * 8;
  float we0[NN], we1[NN];
#pragma unroll
  for (int nn = 0; nn < NN; ++nn) {
    we0[nn] = W_eff[nn * G4 + tid];
    we1[nn] = W_eff[nn * G4 + 256 + tid];
  }
  float b0 = b_ih[tid] + b_hh[tid];
  float b1 = b_ih[256 + tid] + b_hh[256 + tid];
#pragma unroll 8
  for (int n = 0; n < NN; ++n) {
    b0 += biasp[n * G4 + tid];
    b1 += biasp[n * G4 + 256 + tid];
  }
  if (tid < NN) cnt[tid] = 0;
  __syncthreads();
  int es = 0, ed = 0, tk = 0;
  if (tid < ET) {
    if (tid < 96) { es = ei[tid]; ed = ei[96 + tid]; }
    else { es = tid - 96; ed = tid - 96; }
    tk = atomicAdd(&cnt[ed], 1);
  }
  __syncthreads();
  if (tid == 0) {
    offs[0] = 0;
    for (int n = 0; n < NN; ++n) offs[n + 1] = offs[n] + cnt[n];
  }
  if (tid == 1) {
    float cs = 0.f, cd = 0.f;
    for (int f = 0; f < FF; ++f) {
      cs = fmaf(w_gat[f], att_src[f], cs);
      cd = fmaf(w_gat[f], att_dst[f], cd);
    }
    scal_sh[0] = cs;
    scal_sh[1] = cd;
  }
  __syncthreads();
  if (tid < ET) srt[offs[ed] + tk] = es;
  xs[tid] = x_seq[posbase * NN + tid];  // coalesced
  __syncthreads();
  float cs = scal_sh[0], cd = scal_sh[1];
  int p = tid >> 5, n = tid & 31;
  int base = p * 32;
  int e0 = offs[n], e1 = offs[n + 1];
  float xn = xs[base + n];
  float cdxn = cd * xn;
  float m = -3.0e38f;
  for (int e = e0; e < e1; ++e) {
    float ev = fmaf(cs, xs[base + srt[e]], cdxn);
    ev = ev > 0.f ? ev : 0.2f * ev;  // LeakyReLU(0.2)
    m = fmaxf(m, ev);
  }
  float z = 0.f, sa = 0.f;
  for (int e = e0; e < e1; ++e) {
    float xsv = xs[base + srt[e]];
    float ev = fmaf(cs, xsv, cdxn);
    ev = ev > 0.f ? ev : 0.2f * ev;
    float ex = __expf(ev - m);
    z += ex;
    sa = fmaf(ex, xsv, sa);
  }
  sl[p * 32 + n] = sa * frcp(z);
  __syncthreads();
  for (int pp = 0; pp < 8; ++pp) {
    const float4* sp = (const float4*)&sl[pp * 32];
    float a0 = b0, a1 = b1;
#pragma unroll
    for (int q = 0; q < 8; ++q) {
      float4 sv = sp[q];
      a0 = fmaf(sv.x, we0[4 * q], a0);
      a0 = fmaf(sv.y, we0[4 * q + 1], a0);
      a0 = fmaf(sv.z, we0[4 * q + 2], a0);
      a0 = fmaf(sv.w, we0[4 * q + 3], a0);
      a1 = fmaf(sv.x, we1[4 * q], a1);
      a1 = fmaf(sv.y, we1[4 * q + 1], a1);
      a1 = fmaf(sv.z, we1[4 * q + 2], a1);
      a1 = fmaf(sv.w, we1[4 * q + 3], a1);
    }
    size_t row = (size_t)(posbase + pp) * G4;
    xw[row + tid] = a0;
    xw[row + 256 + tid] = a1;
  }
}

// ---------------- LSTM scan: R18 — R13 skeleton, TWO batches per block (shared weights) ----------------
// R13-R17 forensics: not LDS traffic (R15/16), not conflicts (R13 had 0), not lockstep TLP (R17).
// R13's 1267cy/step = ~440cy issue + ~830cy serial critical path (barrier -> ds_read latency ->
// reduce chain -> 2x exp act chain -> write -> barrier) suffered by ALL waves simultaneously.
// R18 fills those bubbles with INDEPENDENT work in the same wave: batch B's FMAs interleave with
// batch A's tail chunks (ATC1-8); weights (128 VGPR) are shared. ~253 VGPR, still 2 waves/SIMD.
// Per-batch path byte-identical to verified R13. One barrier per step covers both batches.
//
// Reg map: v32-63 h (A then B reuse) | v64-191 weights | A: acc v216-223, temps v204-215,
// x-ring v224-227, c v199 | B: acc v228-235, x-ring v236-239, c v240, temps v241-252 |
// v194 xaddr (shared, 2 SGPR bases) | v195/196 rdA/B | v197/198 wrA/B | v200-203 consts

#define PK16F(HP, W0, W1, W2, W3) \
  "v_pk_fma_f32 v[216:217], v[" HP "], v[" W0 "], 0\n\t" \
  "v_pk_fma_f32 v[218:219], v[" HP "], v[" W1 "], 0\n\t" \
  "v_pk_fma_f32 v[220:221], v[" HP "], v[" W2 "], 0\n\t" \
  "v_pk_fma_f32 v[222:223], v[" HP "], v[" W3 "], 0\n\t"

#define PK16A(HP, W0, W1, W2, W3) \
  "v_pk_fma_f32 v[216:217], v[" HP "], v[" W0 "], v[216:217]\n\t" \
  "v_pk_fma_f32 v[218:219], v[" HP "], v[" W1 "], v[218:219]\n\t" \
  "v_pk_fma_f32 v[220:221], v[" HP "], v[" W2 "], v[220:221]\n\t" \
  "v_pk_fma_f32 v[222:223], v[" HP "], v[" W3 "], v[222:223]\n\t"

#define PKB16F(HP, W0, W1, W2, W3) \
  "v_pk_fma_f32 v[228:229], v[" HP "], v[" W0 "], 0\n\t" \
  "v_pk_fma_f32 v[230:231], v[" HP "], v[" W1 "], 0\n\t" \
  "v_pk_fma_f32 v[232:233], v[" HP "], v[" W2 "], 0\n\t" \
  "v_pk_fma_f32 v[234:235], v[" HP "], v[" W3 "], 0\n\t"

#define PKB16A(HP, W0, W1, W2, W3) \
  "v_pk_fma_f32 v[228:229], v[" HP "], v[" W0 "], v[228:229]\n\t" \
  "v_pk_fma_f32 v[230:231], v[" HP "], v[" W1 "], v[230:231]\n\t" \
  "v_pk_fma_f32 v[232:233], v[" HP "], v[" W2 "], v[232:233]\n\t" \
  "v_pk_fma_f32 v[234:235], v[" HP "], v[" W3 "], v[234:235]\n\t"

// ---- A-tail chunks (R13 tail, split; regs v199,v204-215,v216-223 + consts) ----
#define ATC1(XSA) \
  "s_waitcnt vmcnt(7)\n\t" \
  "v_mov_b32 v215, " XSA "\n\t" \
  "global_load_dword " XSA ", v194, %[xwa]\n\t" \
  "v_add_f32 v204, v216, v217\n\t" \
  "v_add_f32 v205, v218, v219\n\t"
#define ATC2 \
  "v_add_f32 v206, v220, v221\n\t" \
  "v_add_f32 v207, v222, v223\n\t" \
  "v_add_f32_dpp v204, v204, v204 quad_perm:[1,0,3,2] row_mask:0xf bank_mask:0xf\n\t" \
  "v_add_f32_dpp v205, v205, v205 quad_perm:[1,0,3,2] row_mask:0xf bank_mask:0xf\n\t" \
  "v_add_f32_dpp v206, v206, v206 quad_perm:[1,0,3,2] row_mask:0xf bank_mask:0xf\n\t"
#define ATC3 \
  "v_add_f32_dpp v207, v207, v207 quad_perm:[1,0,3,2] row_mask:0xf bank_mask:0xf\n\t" \
  "v_add_f32_dpp v204, v204, v204 quad_perm:[2,3,0,1] row_mask:0xf bank_mask:0xf\n\t" \
  "v_add_f32_dpp v205, v205, v205 quad_perm:[2,3,0,1] row_mask:0xf bank_mask:0xf\n\t" \
  "v_add_f32_dpp v206, v206, v206 quad_perm:[2,3,0,1] row_mask:0xf bank_mask:0xf\n\t" \
  "v_add_f32_dpp v207, v207, v207 quad_perm:[2,3,0,1] row_mask:0xf bank_mask:0xf\n\t"
#define ATC4 \
  "v_cndmask_b32 v208, v204, v205, s[22:23]\n\t" \
  "v_cndmask_b32 v209, v206, v207, s[22:23]\n\t" \
  "v_cndmask_b32 v208, v208, v209, s[24:25]\n\t" \
  "v_add_f32 v208, v208, v215\n\t" \
  "v_mul_f32 v209, v200, v208\n\t"
#define ATC5 \
  "v_exp_f32 v209, v209\n\t" \
  "s_nop 0\n\t" \
  "v_add_f32 v209, 1.0, v209\n\t" \
  "v_rcp_f32 v209, v209\n\t" \
  "s_nop 0\n\t"
#define ATC6 \
  "v_fma_f32 v210, v201, v209, v202\n\t" \
  "s_nop 1\n\t" \
  "v_add_f32_dpp v211, v210, v203 quad_perm:[0,0,0,0] row_mask:0xf bank_mask:0xf\n\t" \
  "v_add_f32_dpp v212, v210, v203 quad_perm:[1,1,1,1] row_mask:0xf bank_mask:0xf\n\t" \
  "v_add_f32_dpp v213, v210, v203 quad_perm:[2,2,2,2] row_mask:0xf bank_mask:0xf\n\t"
#define ATC7 \
  "v_add_f32_dpp v214, v210, v203 quad_perm:[3,3,3,3] row_mask:0xf bank_mask:0xf\n\t" \
  "v_mul_f32 v211, v211, v213\n\t" \
  "v_fma_f32 v199, v212, v199, v211\n\t" \
  "v_mul_f32 v209, 0x4038aa3b, v199\n\t"
#define ATC8(WR) \
  "v_exp_f32 v209, v209\n\t" \
  "s_nop 0\n\t" \
  "v_add_f32 v209, 1.0, v209\n\t" \
  "v_rcp_f32 v209, v209\n\t" \
  "s_nop 0\n\t" \
  "v_fma_f32 v209, -2.0, v209, 1.0\n\t" \
  "v_mul_f32 v209, v214, v209\n\t" \
  "ds_write_b32 " WR ", v209\n\t"

// ---- B tail (mirror, regs v240-252 + consts) ----
#define BTAIL(XSB, WR) \
  "s_waitcnt vmcnt(7)\n\t" \
  "v_mov_b32 v241, " XSB "\n\t" \
  "global_load_dword " XSB ", v194, %[xwb2]\n\t" \
  "v_add_u32 v194, 0x800, v194\n\t" \
  "v_add_f32 v242, v228, v229\n\t" \
  "v_add_f32 v243, v230, v231\n\t" \
  "v_add_f32 v244, v232, v233\n\t" \
  "v_add_f32 v245, v234, v235\n\t" \
  "v_add_f32_dpp v242, v242, v242 quad_perm:[1,0,3,2] row_mask:0xf bank_mask:0xf\n\t" \
  "v_add_f32_dpp v243, v243, v243 quad_perm:[1,0,3,2] row_mask:0xf bank_mask:0xf\n\t" \
  "v_add_f32_dpp v244, v244, v244 quad_perm:[1,0,3,2] row_mask:0xf bank_mask:0xf\n\t" \
  "v_add_f32_dpp v245, v245, v245 quad_perm:[1,0,3,2] row_mask:0xf bank_mask:0xf\n\t" \
  "v_add_f32_dpp v242, v242, v242 quad_perm:[2,3,0,1] row_mask:0xf bank_mask:0xf\n\t" \
  "v_add_f32_dpp v243, v243, v243 quad_perm:[2,3,0,1] row_mask:0xf bank_mask:0xf\n\t" \
  "v_add_f32_dpp v244, v244, v244 quad_perm:[2,3,0,1] row_mask:0xf bank_mask:0xf\n\t" \
  "v_add_f32_dpp v245, v245, v245 quad_perm:[2,3,0,1] row_mask:0xf bank_mask:0xf\n\t" \
  "v_cndmask_b32 v246, v242, v243, s[22:23]\n\t" \
  "v_cndmask_b32 v247, v244, v245, s[22:23]\n\t" \
  "v_cndmask_b32 v246, v246, v247, s[24:25]\n\t" \
  "v_add_f32 v246, v246, v241\n\t" \
  "v_mul_f32 v247, v200, v246\n\t" \
  "v_exp_f32 v247, v247\n\t" \
  "s_nop 0\n\t" \
  "v_add_f32 v247, 1.0, v247\n\t" \
  "v_rcp_f32 v247, v247\n\t" \
  "s_nop 0\n\t" \
  "v_fma_f32 v248, v201, v247, v202\n\t" \
  "s_nop 1\n\t" \
  "v_add_f32_dpp v249, v248, v203 quad_perm:[0,0,0,0] row_mask:0xf bank_mask:0xf\n\t" \
  "v_add_f32_dpp v250, v248, v203 quad_perm:[1,1,1,1] row_mask:0xf bank_mask:0xf\n\t" \
  "v_add_f32_dpp v251, v248, v203 quad_perm:[2,2,2,2] row_mask:0xf bank_mask:0xf\n\t" \
  "v_add_f32_dpp v252, v248, v203 quad_perm:[3,3,3,3] row_mask:0xf bank_mask:0xf\n\t" \
  "v_mul_f32 v249, v249, v251\n\t" \
  "v_fma_f32 v240, v250, v240, v249\n\t" \
  "v_mul_f32 v247, 0x4038aa3b, v240\n\t" \
  "v_exp_f32 v247, v247\n\t" \
  "s_nop 0\n\t" \
  "v_add_f32 v247, 1.0, v247\n\t" \
  "v_rcp_f32 v247, v247\n\t" \
  "s_nop 0\n\t" \
  "v_fma_f32 v247, -2.0, v247, 1.0\n\t" \
  "v_mul_f32 v247, v252, v247\n\t" \
  "ds_write_b32 " WR ", v247 offset:1280\n\t"

#define PHASE2(XSA, XSB, RD, WR) \
  "ds_read_b128 v[32:35], " RD "\n\t" \
  "ds_read_b128 v[36:39], " RD " offset:16\n\t" \
  "ds_read_b128 v[40:43], " RD " offset:32\n\t" \
  "ds_read_b128 v[44:47], " RD " offset:48\n\t" \
  "ds_read_b128 v[48:51], " RD " offset:64\n\t" \
  "ds_read_b128 v[52:55], " RD " offset:80\n\t" \
  "ds_read_b128 v[56:59], " RD " offset:96\n\t" \
  "ds_read_b128 v[60:63], " RD " offset:112\n\t" \
  "s_waitcnt lgkmcnt(7)\n\t" \
  PK16F("32:33", "64:65",  "96:97",   "128:129", "160:161") \
  PK16A("34:35", "66:67",  "98:99",   "130:131", "162:163") \
  "s_waitcnt lgkmcnt(6)\n\t" \
  PK16A("36:37", "68:69",  "100:101", "132:133", "164:165") \
  PK16A("38:39", "70:71",  "102:103", "134:135", "166:167") \
  "s_waitcnt lgkmcnt(5)\n\t" \
  PK16A("40:41", "72:73",  "104:105", "136:137", "168:169") \
  PK16A("42:43", "74:75",  "106:107", "138:139", "170:171") \
  "s_waitcnt lgkmcnt(4)\n\t" \
  PK16A("44:45", "76:77",  "108:109", "140:141", "172:173") \
  PK16A("46:47", "78:79",  "110:111", "142:143", "174:175") \
  "s_waitcnt lgkmcnt(3)\n\t" \
  PK16A("48:49", "80:81",  "112:113", "144:145", "176:177") \
  PK16A("50:51", "82:83",  "114:115", "146:147", "178:179") \
  "s_waitcnt lgkmcnt(2)\n\t" \
  PK16A("52:53", "84:85",  "116:117", "148:149", "180:181") \
  PK16A("54:55", "86:87",  "118:119", "150:151", "182:183") \
  "s_waitcnt lgkmcnt(1)\n\t" \
  PK16A("56:57", "88:89",  "120:121", "152:153", "184:185") \
  PK16A("58:59", "90:91",  "122:123", "154:155", "186:187") \
  "s_waitcnt lgkmcnt(0)\n\t" \
  PK16A("60:61", "92:93",  "124:125", "156:157", "188:189") \
  PK16A("62:63", "94:95",  "126:127", "158:159", "190:191") \
  /* ---- B reads (same regs; A consumed them); A-tail head hides read latency ---- */ \
  "ds_read_b128 v[32:35], " RD " offset:1280\n\t" \
  "ds_read_b128 v[36:39], " RD " offset:1296\n\t" \
  "ds_read_b128 v[40:43], " RD " offset:1312\n\t" \
  "ds_read_b128 v[44:47], " RD " offset:1328\n\t" \
  "ds_read_b128 v[48:51], " RD " offset:1344\n\t" \
  "ds_read_b128 v[52:55], " RD " offset:1360\n\t" \
  "ds_read_b128 v[56:59], " RD " offset:1376\n\t" \
  "ds_read_b128 v[60:63], " RD " offset:1392\n\t" \
  ATC1(XSA) \
  ATC2 \
  ATC3 \
  "s_waitcnt lgkmcnt(7)\n\t" \
  PKB16F("32:33", "64:65",  "96:97",   "128:129", "160:161") \
  PKB16A("34:35", "66:67",  "98:99",   "130:131", "162:163") \
  ATC4 \
  "s_waitcnt lgkmcnt(6)\n\t" \
  PKB16A("36:37", "68:69",  "100:101", "132:133", "164:165") \
  PKB16A("38:39", "70:71",  "102:103", "134:135", "166:167") \
  ATC5 \
  "s_waitcnt lgkmcnt(5)\n\t" \
  PKB16A("40:41", "72:73",  "104:105", "136:137", "168:169") \
  PKB16A("42:43", "74:75",  "106:107", "138:139", "170:171") \
  ATC6 \
  "s_waitcnt lgkmcnt(4)\n\t" \
  PKB16A("44:45", "76:77",  "108:109", "140:141", "172:173") \
  PKB16A("46:47", "78:79",  "110:111", "142:143", "174:175") \
  ATC7 \
  "s_waitcnt lgkmcnt(3)\n\t" \
  PKB16A("48:49", "80:81",  "112:113", "144:145", "176:177") \
  PKB16A("50:51", "82:83",  "114:115", "146:147", "178:179") \
  ATC8(WR) \
  "s_waitcnt lgkmcnt(2)\n\t" \
  PKB16A("52:53", "84:85",  "116:117", "148:149", "180:181") \
  PKB16A("54:55", "86:87",  "118:119", "150:151", "182:183") \
  "s_waitcnt lgkmcnt(1)\n\t" \
  PKB16A("56:57", "88:89",  "120:121", "152:153", "184:185") \
  PKB16A("58:59", "90:91",  "122:123", "154:155", "186:187") \
  "s_waitcnt lgkmcnt(0)\n\t" \
  PKB16A("60:61", "92:93",  "124:125", "156:157", "188:189") \
  PKB16A("62:63", "94:95",  "126:127", "158:159", "190:191") \
  BTAIL(XSB, WR) \
  "s_waitcnt lgkmcnt(0)\n\t" \
  "s_barrier\n\t"

__global__ __launch_bounds__(512, 2) void lstm_kernel(const float* __restrict__ xw,
                                                      const float* __restrict__ Wt,
                                                      const float* __restrict__ W_fc,
                                                      const float* __restrict__ b_fc,
                                                      float* __restrict__ out) {
  __shared__ __align__(16) float lds[640];  // A: hA[0,160) hB[160,320); B-batch at +320 floats
  int b = blockIdx.x, tid = threadIdx.x;
  int r = tid >> 2, kq = tid & 3;
  for (int i = tid; i < 640; i += 512) lds[i] = 0.f;
  const float* xwa  = xw + (size_t)(2 * b) * TT * G4;
  const float* xwb2 = xw + (size_t)(2 * b + 1) * TT * G4;
  unsigned xoff0 = (unsigned)((kq * 128 + r) * 4);  // t=0
  unsigned wtoff = (unsigned)(tid * 512);
  unsigned lbase = (unsigned)(uintptr_t)&lds[0];  // LDS aperture is 4GB-aligned
  unsigned rda = lbase + kq * 160;
  unsigned rdb = rda + 640;
  unsigned wra = lbase + (((r >> 5) * 40 + (r & 31)) << 2);
  unsigned wrb = wra + 640;
  // gate-split act constants: lane kq handles gate kq (i,f,o sigmoid; g=2 tanh)
  float kmulf = (kq == 2) ? __uint_as_float(0x4038aa3bu)   //  2*log2e
                          : __uint_as_float(0xbfb8aa3bu);  // -log2e
  float Af = (kq == 2) ? -2.f : 1.f;
  float Bf = (kq == 2) ? 1.f : 0.f;
  unsigned kqodd = kq & 1, kqhi = kq >> 1;
  __syncthreads();
  asm volatile(
    "v_mov_b32 v194, %[xo]\n\t"
    "v_mov_b32 v195, %[rda]\n\t"
    "v_mov_b32 v196, %[rdb]\n\t"
    "v_mov_b32 v197, %[wra]\n\t"
    "v_mov_b32 v198, %[wrb]\n\t"
    "v_mov_b32 v199, 0\n\t"          // c_A
    "v_mov_b32 v240, 0\n\t"          // c_B
    "v_mov_b32 v200, %[km]\n\t"      // kmul
    "v_mov_b32 v201, %[Aa]\n\t"      // A
    "v_mov_b32 v202, %[Bb]\n\t"      // B
    "v_mov_b32 v203, 0\n\t"          // zero (DPP-gather src1)
    "v_cmp_eq_u32 s[22:23], 1, %[kodd]\n\t"
    "v_cmp_eq_u32 s[24:25], 1, %[khi]\n\t"
    // x prefetch rings: A t=0..3 -> v224..v227, B t=0..3 -> v236..v239
    "global_load_dword v224, v194, %[xwa]\n\t"
    "global_load_dword v236, v194, %[xwb2]\n\t"
    "v_add_u32 v194, 0x800, v194\n\t"
    "global_load_dword v225, v194, %[xwa]\n\t"
    "global_load_dword v237, v194, %[xwb2]\n\t"
    "v_add_u32 v194, 0x800, v194\n\t"
    "global_load_dword v226, v194, %[xwa]\n\t"
    "global_load_dword v238, v194, %[xwb2]\n\t"
    "v_add_u32 v194, 0x800, v194\n\t"
    "global_load_dword v227, v194, %[xwa]\n\t"
    "global_load_dword v239, v194, %[xwb2]\n\t"
    "v_add_u32 v194, 0x800, v194\n\t"
    "global_load_dwordx4 v[64:67], %[wto], %[wtb] offset:0\n\t"
    "global_load_dwordx4 v[68:71], %[wto], %[wtb] offset:16\n\t"
    "global_load_dwordx4 v[72:75], %[wto], %[wtb] offset:32\n\t"
    "global_load_dwordx4 v[76:79], %[wto], %[wtb] offset:48\n\t"
    "global_load_dwordx4 v[80:83], %[wto], %[wtb] offset:64\n\t"
    "global_load_dwordx4 v[84:87], %[wto], %[wtb] offset:80\n\t"
    "global_load_dwordx4 v[88:91], %[wto], %[wtb] offset:96\n\t"
    "global_load_dwordx4 v[92:95], %[wto], %[wtb] offset:112\n\t"
    "global_load_dwordx4 v[96:99], %[wto], %[wtb] offset:128\n\t"
    "global_load_dwordx4 v[100:103], %[wto], %[wtb] offset:144\n\t"
    "global_load_dwordx4 v[104:107], %[wto], %[wtb] offset:160\n\t"
    "global_load_dwordx4 v[108:111], %[wto], %[wtb] offset:176\n\t"
    "global_load_dwordx4 v[112:115], %[wto], %[wtb] offset:192\n\t"
    "global_load_dwordx4 v[116:119], %[wto], %[wtb] offset:208\n\t"
    "global_load_dwordx4 v[120:123], %[wto], %[wtb] offset:224\n\t"
    "global_load_dwordx4 v[124:127], %[wto], %[wtb] offset:240\n\t"
    "global_load_dwordx4 v[128:131], %[wto], %[wtb] offset:256\n\t"
    "global_load_dwordx4 v[132:135], %[wto], %[wtb] offset:272\n\t"
    "global_load_dwordx4 v[136:139], %[wto], %[wtb] offset:288\n\t"
    "global_load_dwordx4 v[140:143], %[wto], %[wtb] offset:304\n\t"
    "global_load_dwordx4 v[144:147], %[wto], %[wtb] offset:320\n\t"
    "global_load_dwordx4 v[148:151], %[wto], %[wtb] offset:336\n\t"
    "global_load_dwordx4 v[152:155], %[wto], %[wtb] offset:352\n\t"
    "global_load_dwordx4 v[156:159], %[wto], %[wtb] offset:368\n\t"
    "global_load_dwordx4 v[160:163], %[wto], %[wtb] offset:384\n\t"
    "global_load_dwordx4 v[164:167], %[wto], %[wtb] offset:400\n\t"
    "global_load_dwordx4 v[168:171], %[wto], %[wtb] offset:416\n\t"
    "global_load_dwordx4 v[172:175], %[wto], %[wtb] offset:432\n\t"
    "global_load_dwordx4 v[176:179], %[wto], %[wtb] offset:448\n\t"
    "global_load_dwordx4 v[180:183], %[wto], %[wtb] offset:464\n\t"
    "global_load_dwordx4 v[184:187], %[wto], %[wtb] offset:480\n\t"
    "global_load_dwordx4 v[188:191], %[wto], %[wtb] offset:496\n\t"
    "s_waitcnt vmcnt(0)\n\t"
    "s_movk_i32 s20, 0x80\n\t"    // 128 iterations x 4 phases = 512 steps
    "L_lstm_%=:\n\t"
    PHASE2("v224", "v236", "v195", "v198")   // t%4==0: read A-buf, write B-buf
    PHASE2("v225", "v237", "v196", "v197")   // t%4==1: read B-buf, write A-buf
    PHASE2("v226", "v238", "v195", "v198")   // t%4==2
    PHASE2("v227", "v239", "v196", "v197")   // t%4==3
    "s_sub_u32 s20, s20, 1\n\t"
    "s_cmp_lg_u32 s20, 0\n\t"
    "s_cbranch_scc1 L_lstm_%=\n\t"
    "s_waitcnt vmcnt(0) lgkmcnt(0)\n\t"
    :
    : [xwa]"s"(xwa), [xwb2]"s"(xwb2), [wtb]"s"(Wt), [wto]"v"(wtoff), [xo]"v"(xoff0),
      [rda]"v"(rda), [rdb]"v"(rdb), [wra]"v"(wra), [wrb]"v"(wrb),
      [km]"v"(kmulf), [Aa]"v"(Af), [Bb]"v"(Bf),
      [kodd]"v"(kqodd), [khi]"v"(kqhi)
    : "memory", "scc", "s20", "s22", "s23", "s24", "s25",
      "v32","v33","v34","v35","v36","v37","v38","v39",
      "v40","v41","v42","v43","v44","v45","v46","v47",
      "v48","v49","v50","v51","v52","v53","v54","v55",
      "v56","v57","v58","v59","v60","v61","v62","v63",
      "v64","v65","v66","v67","v68","v69","v70","v71",
      "v72","v73","v74","v75","v76","v77","v78","v79",
      "v80","v81","v82","v83","v84","v85","v86","v87",
      "v88","v89","v90","v91","v92","v93","v94","v95",
      "v96","v97","v98","v99","v100","v101","v102","v103",
      "v104","v105","v106","v107","v108","v109","v110","v111",
      "v112","v113","v114","v115","v116","v117","v118","v119",
      "v120","v121","v122","v123","v124","v125","v126","v127",
      "v128","v129","v130","v131","v132","v133","v134","v135",
      "v136","v137","v138","v139","v140","v141","v142","v143",
      "v144","v145","v146","v147","v148","v149","v150","v151",
      "v152","v153","v154","v155","v156","v157","v158","v159",
      "v160","v161","v162","v163","v164","v165","v166","v167",
      "v168","v169","v170","v171","v172","v173","v174","v175",
      "v176","v177","v178","v179","v180","v181","v182","v183",
      "v184","v185","v186","v187","v188","v189","v190","v191",
      "v192","v193","v194","v195","v196","v197","v198","v199",
      "v200","v201","v202","v203","v204","v205","v206","v207",
      "v208","v209","v210","v211","v212","v213","v214","v215",
      "v216","v217","v218","v219","v220","v221","v222","v223",
      "v224","v225","v226","v227","v228","v229","v230","v231",
      "v232","v233","v234","v235","v236","v237","v238","v239",
      "v240","v241","v242","v243","v244","v245","v246","v247",
      "v248","v249","v250","v251","v252");
  __syncthreads();
  // final h (after t=511) in buffer A of each batch region
  if (tid < 4) {
    float a0 = b_fc[tid], a1 = b_fc[tid];
#pragma unroll 8
    for (int k = 0; k < HH; ++k) {
      int li = (k >> 5) * 40 + (k & 31);
      float wf = W_fc[k * 4 + tid];
      a0 = fmaf(lds[li], wf, a0);
      a1 = fmaf(lds[320 + li], wf, a1);
    }
    out[(2 * b) * 4 + tid] = a0;
    out[(2 * b + 1) * 4 + tid] = a1;
  }
}

extern "C" void kernel_launch(void* const* d_in, const int* in_sizes, int n_in,
                              void* d_out, int out_size, void* d_ws, size_t ws_size,
                              hipStream_t stream) {
  const float* x_seq   = (const float*)d_in[0];
  const int*   ei      = (const int*)d_in[1];
  const float* w_gat   = (const float*)d_in[2];
  const float* att_src = (const float*)d_in[3];
  const float* att_dst = (const float*)d_in[4];
  const float* b_gat   = (const float*)d_in[5];
  const float* W_ih    = (const float*)d_in[6];
  const float* W_hh    = (const float*)d_in[7];
  const float* b_ih    = (const float*)d_in[8];
  const float* b_hh    = (const float*)d_in[9];
  const float* W_fc    = (const float*)d_in[10];
  const float* b_fc    = (const float*)d_in[11];

  float* ws = (float*)d_ws;
  float* Wt    = ws;                            // 512*128 = 65536 f (16B-aligned)
  float* xw    = Wt + 65536;                    // (16384+8)*512 f (pad rows: 4-deep prefetch)
  float* W_eff = xw + (size_t)(NPOS + 8) * G4;  // 32*512
  float* biasp = W_eff + NN * G4;               // 32*512

  prep_kernel<<<NN, G4, 0, stream>>>(w_gat, b_gat, W_ih, W_hh, W_eff, biasp, Wt);
  gatxw_kernel<<<NPOS / 8, 256, 0, stream>>>(x_seq, ei, w_gat, att_src, att_dst,
                                             b_ih, b_hh, W_eff, biasp, xw);
  lstm_kernel<<<BB / 2, 512, 0, stream>>>(xw, Wt, W_fc, b_fc, (float*)d_out);
}

// Round 7
// 374.703 us; speedup vs baseline: 1.5853x; 1.5853x over previous
//
#include <hip/hip_runtime.h>

#define NN 32      // nodes
#define FF 64      // GAT out features
#define HH 128     // LSTM hidden
#define G4 512     // 4*H
#define BB 32      // batch
#define TT 512     // time steps
#define ET 128     // 96 edges + 32 self loops
#define NPOS (BB*TT)
#define POSB 32    // positions per gatxw block (R19: was 8)

__device__ __forceinline__ float frcp(float x) { return __builtin_amdgcn_rcpf(x); }

// ---------------- prep: fold GAT linear into LSTM input weights + Wt transpose ----------------
// R9 weight layout: Wt[tid*128 + g*32 + kk] = W_hh[(kq*32+kk)][g*128 + r], tid=r*4+kq
__global__ __launch_bounds__(512) void prep_kernel(const float* __restrict__ w_gat,
                                                   const float* __restrict__ b_gat,
                                                   const float* __restrict__ W_ih,
                                                   const float* __restrict__ W_hh,
                                                   float* __restrict__ W_eff,
                                                   float* __restrict__ biasp,
                                                   float* __restrict__ Wt) {
  int j = threadIdx.x;
  int n = blockIdx.x;
  float accw = 0.f, accb = 0.f;
#pragma unroll 8
  for (int f = 0; f < FF; ++f) {
    float wv = W_ih[(n * FF + f) * G4 + j];
    accw = fmaf(w_gat[f], wv, accw);
    accb = fmaf(b_gat[f], wv, accb);
  }
  W_eff[n * G4 + j] = accw;
  biasp[n * G4 + j] = accb;
  int g0 = (n * G4 + j) * 4;
#pragma unroll
  for (int q = 0; q < 4; ++q) {
    int e = g0 + q;
    int tl = e >> 7, idx = e & 127;
    int r = tl >> 2, kq = tl & 3;
    int g = idx >> 5, kk = idx & 31;
    Wt[e] = W_hh[(kq * 32 + kk) * G4 + g * 128 + r];
  }
}

// ---------------- fused GAT + xw: R19 — 32 positions per block (4x amortization) ----------------
__global__ __launch_bounds__(256) void gatxw_kernel(const float* __restrict__ x_seq,
                                                    const int* __restrict__ ei,
                                                    const float* __restrict__ w_gat,
                                                    const float* __restrict__ att_src,
                                                    const float* __restrict__ att_dst,
                                                    const float* __restrict__ b_ih,
                                                    const float* __restrict__ b_hh,
                                                    const float* __restrict__ W_eff,
                                                    const float* __restrict__ biasp,
                                                    float* __restrict__ xw) {
  __shared__ int srt[ET];
  __shared__ int offs[NN + 1];
  __shared__ int cnt[NN];
  __shared__ float xs[POSB * NN];   // 1024
  __shared__ float sl[POSB * NN];   // 1024
  __shared__ float scal_sh[2];
  int tid = threadIdx.x;
  int posbase = blockIdx.x * POSB;
  float we0[NN], we1[NN];
#pragma unroll
  for (int nn = 0; nn < NN; ++nn) {
    we0[nn] = W_eff[nn * G4 + tid];
    we1[nn] = W_eff[nn * G4 + 256 + tid];
  }
  float b0 = b_ih[tid] + b_hh[tid];
  float b1 = b_ih[256 + tid] + b_hh[256 + tid];
#pragma unroll 8
  for (int n = 0; n < NN; ++n) {
    b0 += biasp[n * G4 + tid];
    b1 += biasp[n * G4 + 256 + tid];
  }
  if (tid < NN) cnt[tid] = 0;
  __syncthreads();
  int es = 0, ed = 0, tk = 0;
  if (tid < ET) {
    if (tid < 96) { es = ei[tid]; ed = ei[96 + tid]; }
    else { es = tid - 96; ed = tid - 96; }
    tk = atomicAdd(&cnt[ed], 1);
  }
  __syncthreads();
  if (tid == 0) {
    offs[0] = 0;
    for (int n = 0; n < NN; ++n) offs[n + 1] = offs[n] + cnt[n];
  }
  if (tid == 1) {
    float cs = 0.f, cd = 0.f;
    for (int f = 0; f < FF; ++f) {
      cs = fmaf(w_gat[f], att_src[f], cs);
      cd = fmaf(w_gat[f], att_dst[f], cd);
    }
    scal_sh[0] = cs;
    scal_sh[1] = cd;
  }
  __syncthreads();
  if (tid < ET) srt[offs[ed] + tk] = es;
#pragma unroll
  for (int c = 0; c < POSB * NN / 256; ++c)
    xs[c * 256 + tid] = x_seq[posbase * NN + c * 256 + tid];  // coalesced
  __syncthreads();
  float cs = scal_sh[0], cd = scal_sh[1];
  int n = tid & 31;
  int e0 = offs[n], e1 = offs[n + 1];
  // softmax: 4 rounds, thread covers positions pb*8 + (tid>>5)
#pragma unroll
  for (int pb = 0; pb < POSB / 8; ++pb) {
    int p = pb * 8 + (tid >> 5);
    int base = p * 32;
    float xn = xs[base + n];
    float cdxn = cd * xn;
    float m = -3.0e38f;
    for (int e = e0; e < e1; ++e) {
      float ev = fmaf(cs, xs[base + srt[e]], cdxn);
      ev = ev > 0.f ? ev : 0.2f * ev;  // LeakyReLU(0.2)
      m = fmaxf(m, ev);
    }
    float z = 0.f, sa = 0.f;
    for (int e = e0; e < e1; ++e) {
      float xsv = xs[base + srt[e]];
      float ev = fmaf(cs, xsv, cdxn);
      ev = ev > 0.f ? ev : 0.2f * ev;
      float ex = __expf(ev - m);
      z += ex;
      sa = fmaf(ex, xsv, sa);
    }
    sl[base + n] = sa * frcp(z);
  }
  __syncthreads();
#pragma unroll 4
  for (int pp = 0; pp < POSB; ++pp) {
    const float4* sp = (const float4*)&sl[pp * 32];
    float a0 = b0, a1 = b1;
#pragma unroll
    for (int q = 0; q < 8; ++q) {
      float4 sv = sp[q];
      a0 = fmaf(sv.x, we0[4 * q], a0);
      a0 = fmaf(sv.y, we0[4 * q + 1], a0);
      a0 = fmaf(sv.z, we0[4 * q + 2], a0);
      a0 = fmaf(sv.w, we0[4 * q + 3], a0);
      a1 = fmaf(sv.x, we1[4 * q], a1);
      a1 = fmaf(sv.y, we1[4 * q + 1], a1);
      a1 = fmaf(sv.z, we1[4 * q + 2], a1);
      a1 = fmaf(sv.w, we1[4 * q + 3], a1);
    }
    size_t row = (size_t)(posbase + pp) * G4;
    xw[row + tid] = a0;
    xw[row + 256 + tid] = a1;
  }
}

// ---------------- LSTM scan: R13-exact (verified 270us) ----------------
// R13-R18 forensics: step = issue(~710cy, 2 waves/SIMD) + serial chain(~550cy:
// write->barrier->ds_read latency->reduce->2x exp act). Not LDS traffic (R15/16),
// not conflicts (R13=0), not lockstep TLP (R17 worse), not fillable by ILP (R18:
// marginal batch cost 1007cy vs 510 issue). R13 is the optimum of this family;
// 256-thread variants are VGPR-infeasible (R14). Reverted to the verified binary.

#define PK16F(HP, W0, W1, W2, W3) \
  "v_pk_fma_f32 v[216:217], v[" HP "], v[" W0 "], 0\n\t" \
  "v_pk_fma_f32 v[218:219], v[" HP "], v[" W1 "], 0\n\t" \
  "v_pk_fma_f32 v[220:221], v[" HP "], v[" W2 "], 0\n\t" \
  "v_pk_fma_f32 v[222:223], v[" HP "], v[" W3 "], 0\n\t"

#define PK16A(HP, W0, W1, W2, W3) \
  "v_pk_fma_f32 v[216:217], v[" HP "], v[" W0 "], v[216:217]\n\t" \
  "v_pk_fma_f32 v[218:219], v[" HP "], v[" W1 "], v[218:219]\n\t" \
  "v_pk_fma_f32 v[220:221], v[" HP "], v[" W2 "], v[220:221]\n\t" \
  "v_pk_fma_f32 v[222:223], v[" HP "], v[" W3 "], v[222:223]\n\t"

#define PHASE(XSLOT, RD, WR) \
  "ds_read_b128 v[32:35], " RD "\n\t" \
  "ds_read_b128 v[36:39], " RD " offset:16\n\t" \
  "ds_read_b128 v[40:43], " RD " offset:32\n\t" \
  "ds_read_b128 v[44:47], " RD " offset:48\n\t" \
  "ds_read_b128 v[48:51], " RD " offset:64\n\t" \
  "ds_read_b128 v[52:55], " RD " offset:80\n\t" \
  "ds_read_b128 v[56:59], " RD " offset:96\n\t" \
  "ds_read_b128 v[60:63], " RD " offset:112\n\t" \
  "s_waitcnt lgkmcnt(7)\n\t" \
  PK16F("32:33", "64:65",  "96:97",   "128:129", "160:161") \
  PK16A("34:35", "66:67",  "98:99",   "130:131", "162:163") \
  "s_waitcnt lgkmcnt(6)\n\t" \
  PK16A("36:37", "68:69",  "100:101", "132:133", "164:165") \
  PK16A("38:39", "70:71",  "102:103", "134:135", "166:167") \
  "s_waitcnt lgkmcnt(5)\n\t" \
  PK16A("40:41", "72:73",  "104:105", "136:137", "168:169") \
  PK16A("42:43", "74:75",  "106:107", "138:139", "170:171") \
  "s_waitcnt lgkmcnt(4)\n\t" \
  PK16A("44:45", "76:77",  "108:109", "140:141", "172:173") \
  PK16A("46:47", "78:79",  "110:111", "142:143", "174:175") \
  "s_waitcnt lgkmcnt(3)\n\t" \
  PK16A("48:49", "80:81",  "112:113", "144:145", "176:177") \
  PK16A("50:51", "82:83",  "114:115", "146:147", "178:179") \
  "s_waitcnt lgkmcnt(2)\n\t" \
  PK16A("52:53", "84:85",  "116:117", "148:149", "180:181") \
  PK16A("54:55", "86:87",  "118:119", "150:151", "182:183") \
  "s_waitcnt lgkmcnt(1)\n\t" \
  PK16A("56:57", "88:89",  "120:121", "152:153", "184:185") \
  PK16A("58:59", "90:91",  "122:123", "154:155", "186:187") \
  "s_waitcnt lgkmcnt(0)\n\t" \
  PK16A("60:61", "92:93",  "124:125", "156:157", "188:189") \
  PK16A("62:63", "94:95",  "126:127", "158:159", "190:191") \
  "s_waitcnt vmcnt(3)\n\t" \
  "v_mov_b32 v215, " XSLOT "\n\t" \
  "global_load_dword " XSLOT ", v194, %[xwb]\n\t" \
  "v_add_u32 v194, 0x800, v194\n\t" \
  "v_add_f32 v204, v216, v217\n\t" \
  "v_add_f32 v205, v218, v219\n\t" \
  "v_add_f32 v206, v220, v221\n\t" \
  "v_add_f32 v207, v222, v223\n\t" \
  "v_add_f32_dpp v204, v204, v204 quad_perm:[1,0,3,2] row_mask:0xf bank_mask:0xf\n\t" \
  "v_add_f32_dpp v205, v205, v205 quad_perm:[1,0,3,2] row_mask:0xf bank_mask:0xf\n\t" \
  "v_add_f32_dpp v206, v206, v206 quad_perm:[1,0,3,2] row_mask:0xf bank_mask:0xf\n\t" \
  "v_add_f32_dpp v207, v207, v207 quad_perm:[1,0,3,2] row_mask:0xf bank_mask:0xf\n\t" \
  "v_add_f32_dpp v204, v204, v204 quad_perm:[2,3,0,1] row_mask:0xf bank_mask:0xf\n\t" \
  "v_add_f32_dpp v205, v205, v205 quad_perm:[2,3,0,1] row_mask:0xf bank_mask:0xf\n\t" \
  "v_add_f32_dpp v206, v206, v206 quad_perm:[2,3,0,1] row_mask:0xf bank_mask:0xf\n\t" \
  "v_add_f32_dpp v207, v207, v207 quad_perm:[2,3,0,1] row_mask:0xf bank_mask:0xf\n\t" \
  "v_cndmask_b32 v208, v204, v205, s[22:23]\n\t" \
  "v_cndmask_b32 v209, v206, v207, s[22:23]\n\t" \
  "v_cndmask_b32 v208, v208, v209, s[24:25]\n\t" \
  "v_add_f32 v208, v208, v215\n\t" \
  "v_mul_f32 v209, v200, v208\n\t" \
  "v_exp_f32 v209, v209\n\t" \
  "s_nop 0\n\t" \
  "v_add_f32 v209, 1.0, v209\n\t" \
  "v_rcp_f32 v209, v209\n\t" \
  "s_nop 0\n\t" \
  "v_fma_f32 v210, v201, v209, v202\n\t" \
  "s_nop 1\n\t" \
  "v_add_f32_dpp v211, v210, v203 quad_perm:[0,0,0,0] row_mask:0xf bank_mask:0xf\n\t" \
  "v_add_f32_dpp v212, v210, v203 quad_perm:[1,1,1,1] row_mask:0xf bank_mask:0xf\n\t" \
  "v_add_f32_dpp v213, v210, v203 quad_perm:[2,2,2,2] row_mask:0xf bank_mask:0xf\n\t" \
  "v_add_f32_dpp v214, v210, v203 quad_perm:[3,3,3,3] row_mask:0xf bank_mask:0xf\n\t" \
  "v_mul_f32 v211, v211, v213\n\t" \
  "v_fma_f32 v199, v212, v199, v211\n\t" \
  "v_mul_f32 v209, 0x4038aa3b, v199\n\t" \
  "v_exp_f32 v209, v209\n\t" \
  "s_nop 0\n\t" \
  "v_add_f32 v209, 1.0, v209\n\t" \
  "v_rcp_f32 v209, v209\n\t" \
  "s_nop 0\n\t" \
  "v_fma_f32 v209, -2.0, v209, 1.0\n\t" \
  "v_mul_f32 v209, v214, v209\n\t" \
  "ds_write_b32 " WR ", v209\n\t" \
  "s_waitcnt lgkmcnt(0)\n\t" \
  "s_barrier\n\t"

__global__ __launch_bounds__(512, 2) void lstm_kernel(const float* __restrict__ xw,
                                                      const float* __restrict__ Wt,
                                                      const float* __restrict__ W_fc,
                                                      const float* __restrict__ b_fc,
                                                      float* __restrict__ out) {
  __shared__ __align__(16) float lds[320];  // hA [0,160) floats, hB [160,320)
  int b = blockIdx.x, tid = threadIdx.x;
  int r = tid >> 2, kq = tid & 3;
  if (tid < 320) lds[tid] = 0.f;
  const float* xwb = xw + (size_t)b * TT * G4;
  unsigned xoff0 = (unsigned)((kq * 128 + r) * 4);  // t=0
  unsigned wtoff = (unsigned)(tid * 512);
  unsigned lbase = (unsigned)(uintptr_t)&lds[0];  // LDS aperture is 4GB-aligned
  unsigned rda = lbase + kq * 160;
  unsigned rdb = rda + 640;
  unsigned wra = lbase + (((r >> 5) * 40 + (r & 31)) << 2);
  unsigned wrb = wra + 640;
  // gate-split act constants: lane kq handles gate kq (i,f,o sigmoid; g=2 tanh)
  float kmulf = (kq == 2) ? __uint_as_float(0x4038aa3bu)   //  2*log2e
                          : __uint_as_float(0xbfb8aa3bu);  // -log2e
  float Af = (kq == 2) ? -2.f : 1.f;
  float Bf = (kq == 2) ? 1.f : 0.f;
  unsigned kqodd = kq & 1, kqhi = kq >> 1;
  __syncthreads();
  asm volatile(
    "v_mov_b32 v194, %[xo]\n\t"
    "v_mov_b32 v195, %[rda]\n\t"
    "v_mov_b32 v196, %[rdb]\n\t"
    "v_mov_b32 v197, %[wra]\n\t"
    "v_mov_b32 v198, %[wrb]\n\t"
    "v_mov_b32 v199, 0\n\t"          // c
    "v_mov_b32 v200, %[km]\n\t"      // kmul
    "v_mov_b32 v201, %[Aa]\n\t"      // A
    "v_mov_b32 v202, %[Bb]\n\t"      // B
    "v_mov_b32 v203, 0\n\t"          // zero (DPP-gather src1)
    "v_cmp_eq_u32 s[22:23], 1, %[kodd]\n\t"
    "v_cmp_eq_u32 s[24:25], 1, %[khi]\n\t"
    // x prefetch ring: t=0..3 -> v224..v227
    "global_load_dword v224, v194, %[xwb]\n\t"
    "v_add_u32 v194, 0x800, v194\n\t"
    "global_load_dword v225, v194, %[xwb]\n\t"
    "v_add_u32 v194, 0x800, v194\n\t"
    "global_load_dword v226, v194, %[xwb]\n\t"
    "v_add_u32 v194, 0x800, v194\n\t"
    "global_load_dword v227, v194, %[xwb]\n\t"
    "v_add_u32 v194, 0x800, v194\n\t"
    "global_load_dwordx4 v[64:67], %[wto], %[wtb] offset:0\n\t"
    "global_load_dwordx4 v[68:71], %[wto], %[wtb] offset:16\n\t"
    "global_load_dwordx4 v[72:75], %[wto], %[wtb] offset:32\n\t"
    "global_load_dwordx4 v[76:79], %[wto], %[wtb] offset:48\n\t"
    "global_load_dwordx4 v[80:83], %[wto], %[wtb] offset:64\n\t"
    "global_load_dwordx4 v[84:87], %[wto], %[wtb] offset:80\n\t"
    "global_load_dwordx4 v[88:91], %[wto], %[wtb] offset:96\n\t"
    "global_load_dwordx4 v[92:95], %[wto], %[wtb] offset:112\n\t"
    "global_load_dwordx4 v[96:99], %[wto], %[wtb] offset:128\n\t"
    "global_load_dwordx4 v[100:103], %[wto], %[wtb] offset:144\n\t"
    "global_load_dwordx4 v[104:107], %[wto], %[wtb] offset:160\n\t"
    "global_load_dwordx4 v[108:111], %[wto], %[wtb] offset:176\n\t"
    "global_load_dwordx4 v[112:115], %[wto], %[wtb] offset:192\n\t"
    "global_load_dwordx4 v[116:119], %[wto], %[wtb] offset:208\n\t"
    "global_load_dwordx4 v[120:123], %[wto], %[wtb] offset:224\n\t"
    "global_load_dwordx4 v[124:127], %[wto], %[wtb] offset:240\n\t"
    "global_load_dwordx4 v[128:131], %[wto], %[wtb] offset:256\n\t"
    "global_load_dwordx4 v[132:135], %[wto], %[wtb] offset:272\n\t"
    "global_load_dwordx4 v[136:139], %[wto], %[wtb] offset:288\n\t"
    "global_load_dwordx4 v[140:143], %[wto], %[wtb] offset:304\n\t"
    "global_load_dwordx4 v[144:147], %[wto], %[wtb] offset:320\n\t"
    "global_load_dwordx4 v[148:151], %[wto], %[wtb] offset:336\n\t"
    "global_load_dwordx4 v[152:155], %[wto], %[wtb] offset:352\n\t"
    "global_load_dwordx4 v[156:159], %[wto], %[wtb] offset:368\n\t"
    "global_load_dwordx4 v[160:163], %[wto], %[wtb] offset:384\n\t"
    "global_load_dwordx4 v[164:167], %[wto], %[wtb] offset:400\n\t"
    "global_load_dwordx4 v[168:171], %[wto], %[wtb] offset:416\n\t"
    "global_load_dwordx4 v[172:175], %[wto], %[wtb] offset:432\n\t"
    "global_load_dwordx4 v[176:179], %[wto], %[wtb] offset:448\n\t"
    "global_load_dwordx4 v[180:183], %[wto], %[wtb] offset:464\n\t"
    "global_load_dwordx4 v[184:187], %[wto], %[wtb] offset:480\n\t"
    "global_load_dwordx4 v[188:191], %[wto], %[wtb] offset:496\n\t"
    "s_waitcnt vmcnt(0)\n\t"
    "s_movk_i32 s20, 0x80\n\t"    // 128 iterations x 4 phases = 512 steps
    "L_lstm_%=:\n\t"
    PHASE("v224", "v195", "v198")   // t%4==0: read A, write B
    PHASE("v225", "v196", "v197")   // t%4==1: read B, write A
    PHASE("v226", "v195", "v198")   // t%4==2: read A, write B
    PHASE("v227", "v196", "v197")   // t%4==3: read B, write A
    "s_sub_u32 s20, s20, 1\n\t"
    "s_cmp_lg_u32 s20, 0\n\t"
    "s_cbranch_scc1 L_lstm_%=\n\t"
    "s_waitcnt vmcnt(0) lgkmcnt(0)\n\t"
    :
    : [xwb]"s"(xwb), [wtb]"s"(Wt), [wto]"v"(wtoff), [xo]"v"(xoff0),
      [rda]"v"(rda), [rdb]"v"(rdb), [wra]"v"(wra), [wrb]"v"(wrb),
      [km]"v"(kmulf), [Aa]"v"(Af), [Bb]"v"(Bf),
      [kodd]"v"(kqodd), [khi]"v"(kqhi)
    : "memory", "scc", "s20", "s22", "s23", "s24", "s25",
      "v32","v33","v34","v35","v36","v37","v38","v39",
      "v40","v41","v42","v43","v44","v45","v46","v47",
      "v48","v49","v50","v51","v52","v53","v54","v55",
      "v56","v57","v58","v59","v60","v61","v62","v63",
      "v64","v65","v66","v67","v68","v69","v70","v71",
      "v72","v73","v74","v75","v76","v77","v78","v79",
      "v80","v81","v82","v83","v84","v85","v86","v87",
      "v88","v89","v90","v91","v92","v93","v94","v95",
      "v96","v97","v98","v99","v100","v101","v102","v103",
      "v104","v105","v106","v107","v108","v109","v110","v111",
      "v112","v113","v114","v115","v116","v117","v118","v119",
      "v120","v121","v122","v123","v124","v125","v126","v127",
      "v128","v129","v130","v131","v132","v133","v134","v135",
      "v136","v137","v138","v139","v140","v141","v142","v143",
      "v144","v145","v146","v147","v148","v149","v150","v151",
      "v152","v153","v154","v155","v156","v157","v158","v159",
      "v160","v161","v162","v163","v164","v165","v166","v167",
      "v168","v169","v170","v171","v172","v173","v174","v175",
      "v176","v177","v178","v179","v180","v181","v182","v183",
      "v184","v185","v186","v187","v188","v189","v190","v191",
      "v192","v193","v194","v195","v196","v197","v198","v199",
      "v200","v201","v202","v203","v204","v205","v206","v207",
      "v208","v209","v210","v211","v212","v213","v214","v215",
      "v216","v217","v218","v219","v220","v221","v222","v223",
      "v224","v225","v226","v227");
  __syncthreads();
  // final h (after t=511) is in buffer A: lds[(k>>5)*40 + (k&31)]
  if (tid < 4) {
    float acc = b_fc[tid];
#pragma unroll 8
    for (int k = 0; k < HH; ++k)
      acc = fmaf(lds[(k >> 5) * 40 + (k & 31)], W_fc[k * 4 + tid], acc);
    out[b * 4 + tid] = acc;
  }
}

extern "C" void kernel_launch(void* const* d_in, const int* in_sizes, int n_in,
                              void* d_out, int out_size, void* d_ws, size_t ws_size,
                              hipStream_t stream) {
  const float* x_seq   = (const float*)d_in[0];
  const int*   ei      = (const int*)d_in[1];
  const float* w_gat   = (const float*)d_in[2];
  const float* att_src = (const float*)d_in[3];
  const float* att_dst = (const float*)d_in[4];
  const float* b_gat   = (const float*)d_in[5];
  const float* W_ih    = (const float*)d_in[6];
  const float* W_hh    = (const float*)d_in[7];
  const float* b_ih    = (const float*)d_in[8];
  const float* b_hh    = (const float*)d_in[9];
  const float* W_fc    = (const float*)d_in[10];
  const float* b_fc    = (const float*)d_in[11];

  float* ws = (float*)d_ws;
  float* Wt    = ws;                            // 512*128 = 65536 f (16B-aligned)
  float* xw    = Wt + 65536;                    // (16384+8)*512 f (pad rows: 4-deep prefetch)
  float* W_eff = xw + (size_t)(NPOS + 8) * G4;  // 32*512
  float* biasp = W_eff + NN * G4;               // 32*512

  prep_kernel<<<NN, G4, 0, stream>>>(w_gat, b_gat, W_ih, W_hh, W_eff, biasp, Wt);
  gatxw_kernel<<<NPOS / POSB, 256, 0, stream>>>(x_seq, ei, w_gat, att_src, att_dst,
                                                b_ih, b_hh, W_eff, biasp, xw);
  lstm_kernel<<<BB, G4, 0, stream>>>(xw, Wt, W_fc, b_fc, (float*)d_out);
}

// Round 8
// 357.302 us; speedup vs baseline: 1.6625x; 1.0487x over previous
//
#include <hip/hip_runtime.h>
#include <hip/hip_fp16.h>

#define NN 32      // nodes
#define FF 64      // GAT out features
#define HH 128     // LSTM hidden
#define G4 512     // 4*H
#define BB 32      // batch
#define TT 512     // time steps
#define ET 128     // 96 edges + 32 self loops
#define NPOS (BB*TT)
#define POSB 32    // positions per gatxw block

__device__ __forceinline__ float frcp(float x) { return __builtin_amdgcn_rcpf(x); }

// ---------------- prep: fold GAT linear into LSTM input weights + Wt transpose ----------------
// R20 weight layout (f16): thread tid = r*4+kq. Wt16[tid*128 + P*8 + g*2 + e] =
//   f16(W_hh[(kq*32 + 2P + e)][g*128 + r]),  P=0..15 k-pair, g gate, e parity.
// lstm dot2: acc_g += dot2(h_pair[P], w_pair[P][g])  (f32 accumulate)
__global__ __launch_bounds__(512) void prep_kernel(const float* __restrict__ w_gat,
                                                   const float* __restrict__ b_gat,
                                                   const float* __restrict__ W_ih,
                                                   const float* __restrict__ W_hh,
                                                   float* __restrict__ W_eff,
                                                   float* __restrict__ biasp,
                                                   float* __restrict__ Wt) {
  int j = threadIdx.x;
  int n = blockIdx.x;
  float accw = 0.f, accb = 0.f;
#pragma unroll 8
  for (int f = 0; f < FF; ++f) {
    float wv = W_ih[(n * FF + f) * G4 + j];
    accw = fmaf(w_gat[f], wv, accw);
    accb = fmaf(b_gat[f], wv, accb);
  }
  W_eff[n * G4 + j] = accw;
  biasp[n * G4 + j] = accb;
  __half* Wt16 = (__half*)Wt;
  int g0 = (n * G4 + j) * 4;
#pragma unroll
  for (int q = 0; q < 4; ++q) {
    int E = g0 + q;
    int tl = E >> 7, idx = E & 127;
    int r = tl >> 2, kq = tl & 3;
    int P = idx >> 3;            // k-pair 0..15
    int g = (idx >> 1) & 3;      // gate
    int e = idx & 1;             // parity within pair
    int k = kq * 32 + 2 * P + e;
    Wt16[E] = __float2half(W_hh[k * G4 + g * 128 + r]);
  }
}

// ---------------- fused GAT + xw: 32 positions per block ----------------
__global__ __launch_bounds__(256) void gatxw_kernel(const float* __restrict__ x_seq,
                                                    const int* __restrict__ ei,
                                                    const float* __restrict__ w_gat,
                                                    const float* __restrict__ att_src,
                                                    const float* __restrict__ att_dst,
                                                    const float* __restrict__ b_ih,
                                                    const float* __restrict__ b_hh,
                                                    const float* __restrict__ W_eff,
                                                    const float* __restrict__ biasp,
                                                    float* __restrict__ xw) {
  __shared__ int srt[ET];
  __shared__ int offs[NN + 1];
  __shared__ int cnt[NN];
  __shared__ float xs[POSB * NN];   // 1024
  __shared__ float sl[POSB * NN];   // 1024
  __shared__ float scal_sh[2];
  int tid = threadIdx.x;
  int posbase = blockIdx.x * POSB;
  float we0[NN], we1[NN];
#pragma unroll
  for (int nn = 0; nn < NN; ++nn) {
    we0[nn] = W_eff[nn * G4 + tid];
    we1[nn] = W_eff[nn * G4 + 256 + tid];
  }
  float b0 = b_ih[tid] + b_hh[tid];
  float b1 = b_ih[256 + tid] + b_hh[256 + tid];
#pragma unroll 8
  for (int n = 0; n < NN; ++n) {
    b0 += biasp[n * G4 + tid];
    b1 += biasp[n * G4 + 256 + tid];
  }
  if (tid < NN) cnt[tid] = 0;
  __syncthreads();
  int es = 0, ed = 0, tk = 0;
  if (tid < ET) {
    if (tid < 96) { es = ei[tid]; ed = ei[96 + tid]; }
    else { es = tid - 96; ed = tid - 96; }
    tk = atomicAdd(&cnt[ed], 1);
  }
  __syncthreads();
  if (tid == 0) {
    offs[0] = 0;
    for (int n = 0; n < NN; ++n) offs[n + 1] = offs[n] + cnt[n];
  }
  if (tid == 1) {
    float cs = 0.f, cd = 0.f;
    for (int f = 0; f < FF; ++f) {
      cs = fmaf(w_gat[f], att_src[f], cs);
      cd = fmaf(w_gat[f], att_dst[f], cd);
    }
    scal_sh[0] = cs;
    scal_sh[1] = cd;
  }
  __syncthreads();
  if (tid < ET) srt[offs[ed] + tk] = es;
#pragma unroll
  for (int c = 0; c < POSB * NN / 256; ++c)
    xs[c * 256 + tid] = x_seq[posbase * NN + c * 256 + tid];  // coalesced
  __syncthreads();
  float cs = scal_sh[0], cd = scal_sh[1];
  int n = tid & 31;
  int e0 = offs[n], e1 = offs[n + 1];
#pragma unroll
  for (int pb = 0; pb < POSB / 8; ++pb) {
    int p = pb * 8 + (tid >> 5);
    int base = p * 32;
    float xn = xs[base + n];
    float cdxn = cd * xn;
    float m = -3.0e38f;
    for (int e = e0; e < e1; ++e) {
      float ev = fmaf(cs, xs[base + srt[e]], cdxn);
      ev = ev > 0.f ? ev : 0.2f * ev;  // LeakyReLU(0.2)
      m = fmaxf(m, ev);
    }
    float z = 0.f, sa = 0.f;
    for (int e = e0; e < e1; ++e) {
      float xsv = xs[base + srt[e]];
      float ev = fmaf(cs, xsv, cdxn);
      ev = ev > 0.f ? ev : 0.2f * ev;
      float ex = __expf(ev - m);
      z += ex;
      sa = fmaf(ex, xsv, sa);
    }
    sl[base + n] = sa * frcp(z);
  }
  __syncthreads();
#pragma unroll 4
  for (int pp = 0; pp < POSB; ++pp) {
    const float4* sp = (const float4*)&sl[pp * 32];
    float a0 = b0, a1 = b1;
#pragma unroll
    for (int q = 0; q < 8; ++q) {
      float4 sv = sp[q];
      a0 = fmaf(sv.x, we0[4 * q], a0);
      a0 = fmaf(sv.y, we0[4 * q + 1], a0);
      a0 = fmaf(sv.z, we0[4 * q + 2], a0);
      a0 = fmaf(sv.w, we0[4 * q + 3], a0);
      a1 = fmaf(sv.x, we1[4 * q], a1);
      a1 = fmaf(sv.y, we1[4 * q + 1], a1);
      a1 = fmaf(sv.z, we1[4 * q + 2], a1);
      a1 = fmaf(sv.w, we1[4 * q + 3], a1);
    }
    size_t row = (size_t)(posbase + pp) * G4;
    xw[row + tid] = a0;
    xw[row + 256 + tid] = a1;
  }
}

// ---------------- LSTM scan: R20 — R13 skeleton, f16 weights+h via v_dot2_f32_f16 ----------------
// R13-R18 model: step = issue(~480cy) + serial chain(~550cy). Issue at 512thr is invariant
// under f32 repartitions; dot2_f32_f16 shrinks it: weights 128->64 VGPR (16 loads), h reads
// 8->4 ds_read_b128/step, accs become scalar-f32 per gate (no pk-half folds in tail).
// Activations/c/x stay f32 (f32 accumulate => gate pre-act err ~3e-4).
//
// Reg map: v32-47 h f16-pairs | v64-127 weights f16 | v216-219 acc (f32, gate=idx)
// v204-215 tail temps | v224-227 x ring | v194 xaddr | v195/196 rdA/B | v197/198 wrA/B
// v199 c | v200-203 act consts/zero

#define D2F(HJ, W0, W1, W2, W3) \
  "v_dot2_f32_f16 v216, v" HJ ", v" W0 ", 0\n\t" \
  "v_dot2_f32_f16 v217, v" HJ ", v" W1 ", 0\n\t" \
  "v_dot2_f32_f16 v218, v" HJ ", v" W2 ", 0\n\t" \
  "v_dot2_f32_f16 v219, v" HJ ", v" W3 ", 0\n\t"

#define D2A(HJ, W0, W1, W2, W3) \
  "v_dot2_f32_f16 v216, v" HJ ", v" W0 ", v216\n\t" \
  "v_dot2_f32_f16 v217, v" HJ ", v" W1 ", v217\n\t" \
  "v_dot2_f32_f16 v218, v" HJ ", v" W2 ", v218\n\t" \
  "v_dot2_f32_f16 v219, v" HJ ", v" W3 ", v219\n\t"

#define PHASE(XSLOT, RD, WR) \
  "ds_read_b128 v[32:35], " RD "\n\t" \
  "ds_read_b128 v[36:39], " RD " offset:16\n\t" \
  "ds_read_b128 v[40:43], " RD " offset:32\n\t" \
  "ds_read_b128 v[44:47], " RD " offset:48\n\t" \
  "s_waitcnt lgkmcnt(3)\n\t" \
  D2F("32", "64", "65", "66", "67") \
  D2A("33", "68", "69", "70", "71") \
  D2A("34", "72", "73", "74", "75") \
  D2A("35", "76", "77", "78", "79") \
  "s_waitcnt lgkmcnt(2)\n\t" \
  D2A("36", "80", "81", "82", "83") \
  D2A("37", "84", "85", "86", "87") \
  D2A("38", "88", "89", "90", "91") \
  D2A("39", "92", "93", "94", "95") \
  "s_waitcnt lgkmcnt(1)\n\t" \
  D2A("40", "96", "97", "98", "99") \
  D2A("41", "100", "101", "102", "103") \
  D2A("42", "104", "105", "106", "107") \
  D2A("43", "108", "109", "110", "111") \
  "s_waitcnt lgkmcnt(0)\n\t" \
  D2A("44", "112", "113", "114", "115") \
  D2A("45", "116", "117", "118", "119") \
  D2A("46", "120", "121", "122", "123") \
  D2A("47", "124", "125", "126", "127") \
  "v_add_f32_dpp v216, v216, v216 quad_perm:[1,0,3,2] row_mask:0xf bank_mask:0xf\n\t" \
  "v_add_f32_dpp v217, v217, v217 quad_perm:[1,0,3,2] row_mask:0xf bank_mask:0xf\n\t" \
  "v_add_f32_dpp v218, v218, v218 quad_perm:[1,0,3,2] row_mask:0xf bank_mask:0xf\n\t" \
  "v_add_f32_dpp v219, v219, v219 quad_perm:[1,0,3,2] row_mask:0xf bank_mask:0xf\n\t" \
  "v_add_f32_dpp v216, v216, v216 quad_perm:[2,3,0,1] row_mask:0xf bank_mask:0xf\n\t" \
  "v_add_f32_dpp v217, v217, v217 quad_perm:[2,3,0,1] row_mask:0xf bank_mask:0xf\n\t" \
  "v_add_f32_dpp v218, v218, v218 quad_perm:[2,3,0,1] row_mask:0xf bank_mask:0xf\n\t" \
  "v_add_f32_dpp v219, v219, v219 quad_perm:[2,3,0,1] row_mask:0xf bank_mask:0xf\n\t" \
  "v_cndmask_b32 v208, v216, v217, s[22:23]\n\t" \
  "v_cndmask_b32 v209, v218, v219, s[22:23]\n\t" \
  "v_cndmask_b32 v208, v208, v209, s[24:25]\n\t" \
  "s_waitcnt vmcnt(3)\n\t" \
  "v_mov_b32 v215, " XSLOT "\n\t" \
  "global_load_dword " XSLOT ", v194, %[xwb]\n\t" \
  "v_add_u32 v194, 0x800, v194\n\t" \
  "v_add_f32 v208, v208, v215\n\t" \
  "v_mul_f32 v209, v200, v208\n\t" \
  "v_exp_f32 v209, v209\n\t" \
  "s_nop 0\n\t" \
  "v_add_f32 v209, 1.0, v209\n\t" \
  "v_rcp_f32 v209, v209\n\t" \
  "s_nop 0\n\t" \
  "v_fma_f32 v210, v201, v209, v202\n\t" \
  "s_nop 1\n\t" \
  "v_add_f32_dpp v211, v210, v203 quad_perm:[0,0,0,0] row_mask:0xf bank_mask:0xf\n\t" \
  "v_add_f32_dpp v212, v210, v203 quad_perm:[1,1,1,1] row_mask:0xf bank_mask:0xf\n\t" \
  "v_add_f32_dpp v213, v210, v203 quad_perm:[2,2,2,2] row_mask:0xf bank_mask:0xf\n\t" \
  "v_add_f32_dpp v214, v210, v203 quad_perm:[3,3,3,3] row_mask:0xf bank_mask:0xf\n\t" \
  "v_mul_f32 v211, v211, v213\n\t" \
  "v_fma_f32 v199, v212, v199, v211\n\t" \
  "v_mul_f32 v209, 0x4038aa3b, v199\n\t" \
  "v_exp_f32 v209, v209\n\t" \
  "s_nop 0\n\t" \
  "v_add_f32 v209, 1.0, v209\n\t" \
  "v_rcp_f32 v209, v209\n\t" \
  "s_nop 0\n\t" \
  "v_fma_f32 v209, -2.0, v209, 1.0\n\t" \
  "v_mul_f32 v209, v214, v209\n\t" \
  "v_cvt_f16_f32 v209, v209\n\t" \
  "ds_write_b16 " WR ", v209\n\t" \
  "s_waitcnt lgkmcnt(0)\n\t" \
  "s_barrier\n\t"

__global__ __launch_bounds__(512, 2) void lstm_kernel(const float* __restrict__ xw,
                                                      const float* __restrict__ Wt,
                                                      const float* __restrict__ W_fc,
                                                      const float* __restrict__ b_fc,
                                                      float* __restrict__ out) {
  __shared__ __align__(16) float lds[160];  // f16 storage: hA bytes [0,320), hB [320,640)
  int b = blockIdx.x, tid = threadIdx.x;
  int r = tid >> 2, kq = tid & 3;
  if (tid < 160) lds[tid] = 0.f;            // f16 zeros
  const float* xwb = xw + (size_t)b * TT * G4;
  unsigned xoff0 = (unsigned)((kq * 128 + r) * 4);  // t=0 (xw is f32)
  unsigned wtoff = (unsigned)(tid * 256);           // 128 f16 = 256 B per thread
  unsigned lbase = (unsigned)(uintptr_t)&lds[0];    // LDS aperture is 4GB-aligned
  unsigned rda = lbase + (unsigned)(kq * 80);       // quarter kq: 32 f16 = 64B (stripe 40 f16)
  unsigned rdb = rda + 320;
  unsigned wra = lbase + (unsigned)(((r >> 5) * 40 + (r & 31)) * 2);  // f16 element
  unsigned wrb = wra + 320;
  // gate-split act constants: lane kq handles gate kq (i,f,o sigmoid; g=2 tanh)
  float kmulf = (kq == 2) ? __uint_as_float(0x4038aa3bu)   //  2*log2e
                          : __uint_as_float(0xbfb8aa3bu);  // -log2e
  float Af = (kq == 2) ? -2.f : 1.f;
  float Bf = (kq == 2) ? 1.f : 0.f;
  unsigned kqodd = kq & 1, kqhi = kq >> 1;
  __syncthreads();
  asm volatile(
    "v_mov_b32 v194, %[xo]\n\t"
    "v_mov_b32 v195, %[rda]\n\t"
    "v_mov_b32 v196, %[rdb]\n\t"
    "v_mov_b32 v197, %[wra]\n\t"
    "v_mov_b32 v198, %[wrb]\n\t"
    "v_mov_b32 v199, 0\n\t"          // c
    "v_mov_b32 v200, %[km]\n\t"      // kmul
    "v_mov_b32 v201, %[Aa]\n\t"      // A
    "v_mov_b32 v202, %[Bb]\n\t"      // B
    "v_mov_b32 v203, 0\n\t"          // zero (DPP-gather src1)
    "v_cmp_eq_u32 s[22:23], 1, %[kodd]\n\t"
    "v_cmp_eq_u32 s[24:25], 1, %[khi]\n\t"
    // x prefetch ring: t=0..3 -> v224..v227
    "global_load_dword v224, v194, %[xwb]\n\t"
    "v_add_u32 v194, 0x800, v194\n\t"
    "global_load_dword v225, v194, %[xwb]\n\t"
    "v_add_u32 v194, 0x800, v194\n\t"
    "global_load_dword v226, v194, %[xwb]\n\t"
    "v_add_u32 v194, 0x800, v194\n\t"
    "global_load_dword v227, v194, %[xwb]\n\t"
    "v_add_u32 v194, 0x800, v194\n\t"
    // 128 f16 weights -> v64..v127 (16 x dwordx4)
    "global_load_dwordx4 v[64:67], %[wto], %[wtb] offset:0\n\t"
    "global_load_dwordx4 v[68:71], %[wto], %[wtb] offset:16\n\t"
    "global_load_dwordx4 v[72:75], %[wto], %[wtb] offset:32\n\t"
    "global_load_dwordx4 v[76:79], %[wto], %[wtb] offset:48\n\t"
    "global_load_dwordx4 v[80:83], %[wto], %[wtb] offset:64\n\t"
    "global_load_dwordx4 v[84:87], %[wto], %[wtb] offset:80\n\t"
    "global_load_dwordx4 v[88:91], %[wto], %[wtb] offset:96\n\t"
    "global_load_dwordx4 v[92:95], %[wto], %[wtb] offset:112\n\t"
    "global_load_dwordx4 v[96:99], %[wto], %[wtb] offset:128\n\t"
    "global_load_dwordx4 v[100:103], %[wto], %[wtb] offset:144\n\t"
    "global_load_dwordx4 v[104:107], %[wto], %[wtb] offset:160\n\t"
    "global_load_dwordx4 v[108:111], %[wto], %[wtb] offset:176\n\t"
    "global_load_dwordx4 v[112:115], %[wto], %[wtb] offset:192\n\t"
    "global_load_dwordx4 v[116:119], %[wto], %[wtb] offset:208\n\t"
    "global_load_dwordx4 v[120:123], %[wto], %[wtb] offset:224\n\t"
    "global_load_dwordx4 v[124:127], %[wto], %[wtb] offset:240\n\t"
    "s_waitcnt vmcnt(0)\n\t"
    "s_movk_i32 s20, 0x80\n\t"    // 128 iterations x 4 phases = 512 steps
    "L_lstm_%=:\n\t"
    PHASE("v224", "v195", "v198")   // t%4==0: read A, write B
    PHASE("v225", "v196", "v197")   // t%4==1: read B, write A
    PHASE("v226", "v195", "v198")   // t%4==2: read A, write B
    PHASE("v227", "v196", "v197")   // t%4==3: read B, write A
    "s_sub_u32 s20, s20, 1\n\t"
    "s_cmp_lg_u32 s20, 0\n\t"
    "s_cbranch_scc1 L_lstm_%=\n\t"
    "s_waitcnt vmcnt(0) lgkmcnt(0)\n\t"
    :
    : [xwb]"s"(xwb), [wtb]"s"(Wt), [wto]"v"(wtoff), [xo]"v"(xoff0),
      [rda]"v"(rda), [rdb]"v"(rdb), [wra]"v"(wra), [wrb]"v"(wrb),
      [km]"v"(kmulf), [Aa]"v"(Af), [Bb]"v"(Bf),
      [kodd]"v"(kqodd), [khi]"v"(kqhi)
    : "memory", "scc", "s20", "s22", "s23", "s24", "s25",
      "v32","v33","v34","v35","v36","v37","v38","v39",
      "v40","v41","v42","v43","v44","v45","v46","v47",
      "v64","v65","v66","v67","v68","v69","v70","v71",
      "v72","v73","v74","v75","v76","v77","v78","v79",
      "v80","v81","v82","v83","v84","v85","v86","v87",
      "v88","v89","v90","v91","v92","v93","v94","v95",
      "v96","v97","v98","v99","v100","v101","v102","v103",
      "v104","v105","v106","v107","v108","v109","v110","v111",
      "v112","v113","v114","v115","v116","v117","v118","v119",
      "v120","v121","v122","v123","v124","v125","v126","v127",
      "v194","v195","v196","v197","v198","v199",
      "v200","v201","v202","v203","v204","v205","v206","v207",
      "v208","v209","v210","v211","v212","v213","v214","v215",
      "v216","v217","v218","v219",
      "v224","v225","v226","v227");
  __syncthreads();
  // final h (after t=511) is in buffer A as f16: stripe idx (k>>5)*40 + (k&31)
  if (tid < 4) {
    const __half* hf = (const __half*)lds;
    float acc = b_fc[tid];
#pragma unroll 8
    for (int k = 0; k < HH; ++k)
      acc = fmaf(__half2float(hf[(k >> 5) * 40 + (k & 31)]), W_fc[k * 4 + tid], acc);
    out[b * 4 + tid] = acc;
  }
}

extern "C" void kernel_launch(void* const* d_in, const int* in_sizes, int n_in,
                              void* d_out, int out_size, void* d_ws, size_t ws_size,
                              hipStream_t stream) {
  const float* x_seq   = (const float*)d_in[0];
  const int*   ei      = (const int*)d_in[1];
  const float* w_gat   = (const float*)d_in[2];
  const float* att_src = (const float*)d_in[3];
  const float* att_dst = (const float*)d_in[4];
  const float* b_gat   = (const float*)d_in[5];
  const float* W_ih    = (const float*)d_in[6];
  const float* W_hh    = (const float*)d_in[7];
  const float* b_ih    = (const float*)d_in[8];
  const float* b_hh    = (const float*)d_in[9];
  const float* W_fc    = (const float*)d_in[10];
  const float* b_fc    = (const float*)d_in[11];

  float* ws = (float*)d_ws;
  float* Wt    = ws;                            // 65536 f16 used (region reserved as 65536 f32)
  float* xw    = Wt + 65536;                    // (16384+8)*512 f (pad rows: 4-deep prefetch)
  float* W_eff = xw + (size_t)(NPOS + 8) * G4;  // 32*512
  float* biasp = W_eff + NN * G4;               // 32*512

  prep_kernel<<<NN, G4, 0, stream>>>(w_gat, b_gat, W_ih, W_hh, W_eff, biasp, Wt);
  gatxw_kernel<<<NPOS / POSB, 256, 0, stream>>>(x_seq, ei, w_gat, att_src, att_dst,
                                                b_ih, b_hh, W_eff, biasp, xw);
  lstm_kernel<<<BB, G4, 0, stream>>>(xw, Wt, W_fc, b_fc, (float*)d_out);
}